// Round 1
// baseline (209.697 us; speedup 1.0000x reference)
//
#include <hip/hip_runtime.h>

#define DT_C   1.0f
#define EPS_C  1e-12f
#define BETA_MIN_C 1e-4f
#define HCHUNK 8          // h-steps staged in LDS per store phase
#define BLK 256

// One thread per (b, m). Sequential H-step SIR rollout in registers.
// Same per-step math as the 207us version (bit-identical values, absmax 256):
//   inc = S*I*binv  (binv = beta/(n+EPS) hoisted, exact div once)
//   scale = n * rcp_nr(total+EPS)
//
// New vs previous version: stores are staged through LDS so they issue as
// global_store_dwordx4 (16 B/lane, 1 KiB/wave) instead of dword (4 B/lane).
// Layout [B,H,M] forbids per-thread wide stores across h; the LDS transpose
// (compute-thread -> store-thread remap within the block) enables them.
// Double-buffered LDS, ONE barrier per 8-step chunk:
//   write lds[p] -> barrier -> {store lds[p] || compute next chunk into lds[p^1]}
// Reads of lds[p^1] (previous chunk's store phase) are separated from the next
// write to lds[p^1] by the intervening barrier.
__global__ void __launch_bounds__(BLK)
sir_rollout_kernel(const float* __restrict__ feature,
                   const float* __restrict__ logbeta,
                   const float* __restrict__ loggamma,
                   const float* __restrict__ Nvec,
                   float* __restrict__ out,
                   int B, int W, int M, int F, int H) {
    __shared__ float lds[2][HCHUNK][BLK];   // 2 * 8 * 256 * 4 = 16 KiB

    const int tid       = threadIdx.x;
    const int blockBase = blockIdx.x * BLK;
    const int idx       = blockBase + tid;          // idx = b*M + m
    const int total     = B * M;
    const bool active   = (idx < total);

    const float beta  = (tanhf(logbeta[0])  + 1.0f) * 0.5f;
    const float gamma = (tanhf(loggamma[0]) + 1.0f) * 0.5f;
    const float beta_safe = fmaxf(beta, BETA_MIN_C);

    float n = 0.0f, binv = 0.0f, S = 0.0f, I = 0.0f, R = 0.0f;
    if (active) {
        const int b = idx / M;
        const int m = idx - b * M;
        n    = Nvec[m];
        binv = beta / (n + EPS_C);                 // exact div, hoisted
        const size_t fidx = ((size_t)(b * W + (W - 1)) * (size_t)M + (size_t)m) * (size_t)F;
        const float c0 = fmaxf(feature[fidx], 0.0f);
        I = fminf(fmaxf(c0 / beta_safe, 0.0f), n); // exact div, once
        S = fmaxf(n - I, 0.0f);
        R = 0.0f;
    }

    const int hc_count = H / HCHUNK;
    int buf = 0;

    for (int hc = 0; hc < hc_count; ++hc) {
        // ---- compute HCHUNK steps into lds[buf] (stride-4B writes: conflict-free)
        #pragma unroll
        for (int j = 0; j < HCHUNK; ++j) {
            const float inc = S * I * binv;        // == beta*S*I/(n+EPS) to ~1 ulp
            lds[buf][j][tid] = inc;                // DT == 1.0f exactly

            const float gI = gamma * I;
            const float nS = fmaxf(S - inc, 0.0f);
            const float nI = fmaxf(I + (inc - gI), 0.0f);
            const float nR = fmaxf(R + gI, 0.0f);

            const float t  = (nS + nI + nR) + EPS_C;
            float r = __builtin_amdgcn_rcpf(t);    // v_rcp_f32
            r = r + r * fmaf(-t, r, 1.0f);         // NR refine -> ~0.5-2 ulp
            const float scale = n * r;

            S = nS * scale;
            I = nI * scale;
            R = nR * scale;
        }

        __syncthreads();

        // ---- cooperative wide store of lds[buf]: HCHUNK*BLK floats = 512 float4
        // float4 q: j = q/64 (64 float4 per 256-float row), c4 = (q%64)*4.
        // Global chain for that float4 = blockBase + c4 (aligned group of 4
        // consecutive idx -> same b, consecutive m, since M % 4 == 0).
        const int hbase = hc * HCHUNK;
        #pragma unroll
        for (int k = 0; k < 2; ++k) {
            const int q    = tid + k * BLK;
            const int j    = q >> 6;
            const int c4   = (q & 63) << 2;
            const int gidx = blockBase + c4;
            if (gidx + 3 < total) {
                const int bq = gidx / M;
                const int mq = gidx - bq * M;
                const float4 v = *reinterpret_cast<const float4*>(&lds[buf][j][c4]);
                *reinterpret_cast<float4*>(
                    out + ((size_t)bq * (size_t)H + (size_t)(hbase + j)) * (size_t)M + (size_t)mq) = v;
            }
        }
        buf ^= 1;
    }

    // ---- tail (H % HCHUNK != 0) — not hit for H=256, kept for generality
    if (active) {
        const int b = idx / M;
        const int m = idx - b * M;
        float* o = out + (size_t)b * (size_t)H * (size_t)M + (size_t)m;
        for (int h = hc_count * HCHUNK; h < H; ++h) {
            const float inc = S * I * binv;
            o[(size_t)h * (size_t)M] = inc;
            const float gI = gamma * I;
            const float nS = fmaxf(S - inc, 0.0f);
            const float nI = fmaxf(I + (inc - gI), 0.0f);
            const float nR = fmaxf(R + gI, 0.0f);
            const float t  = (nS + nI + nR) + EPS_C;
            float r = __builtin_amdgcn_rcpf(t);
            r = r + r * fmaf(-t, r, 1.0f);
            const float scale = n * r;
            S = nS * scale;
            I = nI * scale;
            R = nR * scale;
        }
    }
}

extern "C" void kernel_launch(void* const* d_in, const int* in_sizes, int n_in,
                              void* d_out, int out_size, void* d_ws, size_t ws_size,
                              hipStream_t stream) {
    const float* feature  = (const float*)d_in[0];
    const float* logbeta  = (const float*)d_in[1];
    const float* loggamma = (const float*)d_in[2];
    const float* Nvec     = (const float*)d_in[3];
    float* out = (float*)d_out;

    const int M = in_sizes[3];                    // 4096
    const int B = 32;                             // reference setup
    const int F = 8;                              // reference setup
    const int W = in_sizes[0] / (B * M * F);      // 32
    const int H = out_size / (B * M);             // 256

    const int nthreads = B * M;                   // 131072
    const int grid = (nthreads + BLK - 1) / BLK;  // 512

    sir_rollout_kernel<<<grid, BLK, 0, stream>>>(feature, logbeta, loggamma,
                                                 Nvec, out, B, W, M, F, H);
}